// Round 1
// baseline (727.395 us; speedup 1.0000x reference)
//
#include <hip/hip_runtime.h>
#include <stdint.h>

#define N_NODES 8192
#define IN_F    512
#define OUT_F   256
#define ALPHA   0.2f

typedef __attribute__((ext_vector_type(8))) short bf16x8;
typedef __attribute__((ext_vector_type(4))) float f32x4;

__device__ __forceinline__ uint32_t f32_to_bf16(float f) {
    union { float f; uint32_t u; } v; v.f = f;
    uint32_t u = v.u;
    return (u + 0x7fffu + ((u >> 16) & 1u)) >> 16;   // RNE
}

// ---------------------------------------------------------------------------
// K0: w1 = W^T a1, w2 = W^T a2  (w12[0:512]=w1, w12[512:1024]=w2)
// grid 32 blocks x 256 thr; block b covers W rows [8b, 8b+8); atomicAdd.
// ---------------------------------------------------------------------------
__global__ __launch_bounds__(256) void k0_wvec(
    const float* __restrict__ W, const float* __restrict__ a_vec,
    float* __restrict__ w12)
{
    const int t  = threadIdx.x;
    const int nb = blockIdx.x * 8;
    float a1lo = 0.f, a1hi = 0.f, a2lo = 0.f, a2hi = 0.f;
    #pragma unroll
    for (int q = 0; q < 8; q++) {
        int n = nb + q;
        float lo = W[(size_t)n * IN_F + t];
        float hi = W[(size_t)n * IN_F + t + 256];
        float a1 = a_vec[n], a2 = a_vec[OUT_F + n];
        a1lo = fmaf(lo, a1, a1lo); a1hi = fmaf(hi, a1, a1hi);
        a2lo = fmaf(lo, a2, a2lo); a2hi = fmaf(hi, a2, a2hi);
    }
    atomicAdd(&w12[t], a1lo);       atomicAdd(&w12[t + 256], a1hi);
    atomicAdd(&w12[512 + t], a2lo); atomicAdd(&w12[512 + t + 256], a2hi);
}

// ---------------------------------------------------------------------------
// Ks: s_src[i] = h[i] . w1 ; s_dst[i] = h[i] . w2   (1 wave per row)
// ---------------------------------------------------------------------------
__global__ __launch_bounds__(256) void ks_svec(
    const float* __restrict__ h, const float* __restrict__ w12,
    float* __restrict__ s_src, float* __restrict__ s_dst)
{
    __shared__ float sw[1024];
    const int t = threadIdx.x;
    #pragma unroll
    for (int q = 0; q < 4; q++) sw[q * 256 + t] = w12[q * 256 + t];
    __syncthreads();
    const int w = t >> 6, ln = t & 63;
    const int i = blockIdx.x * 4 + w;
    const float* hr = h + (size_t)i * IN_F + ln * 8;
    float4 h0 = *(const float4*)hr;
    float4 h1 = *(const float4*)(hr + 4);
    const float* w1 = sw + ln * 8;
    const float* w2 = sw + 512 + ln * 8;
    float v1 = h0.x*w1[0] + h0.y*w1[1] + h0.z*w1[2] + h0.w*w1[3]
             + h1.x*w1[4] + h1.y*w1[5] + h1.z*w1[6] + h1.w*w1[7];
    float v2 = h0.x*w2[0] + h0.y*w2[1] + h0.z*w2[2] + h0.w*w2[3]
             + h1.x*w2[4] + h1.y*w2[5] + h1.z*w2[6] + h1.w*w2[7];
    #pragma unroll
    for (int off = 32; off >= 1; off >>= 1) {
        v1 += __shfl_xor(v1, off, 64);
        v2 += __shfl_xor(v2, off, 64);
    }
    if (ln == 0) { s_src[i] = v1; s_dst[i] = v2; }
}

// ---------------------------------------------------------------------------
// K1: Wh = h @ W^T (fp32) -> whf bf16 in MFMA-B-fragment-major layout.
// chunk c = (j>>5)*16 + (n>>4); within: lane = (n&15) + ((j>>3)&3)*16,
// element = lane*8 + (j&7).   grid (4 colblk, 128 rowblk), 256 thr, 4x4/thr.
// LDS stride 68 (=17*16B): keeps &As[kk][tm*4] 16B-aligned -> ds_read_b128.
// ---------------------------------------------------------------------------
__global__ __launch_bounds__(256) void k1_wh_pack(
    const float* __restrict__ h, const float* __restrict__ W,
    uint16_t* __restrict__ whf)
{
    const int n0 = blockIdx.x * 64, i0 = blockIdx.y * 64;
    const int t  = threadIdx.x;
    const int tn = t & 15, tm = t >> 4;

    __shared__ float As[32][68];
    __shared__ float Bs[32][68];

    float acc[4][4];
    #pragma unroll
    for (int i = 0; i < 4; i++)
        #pragma unroll
        for (int j = 0; j < 4; j++) acc[i][j] = 0.f;

    for (int k0 = 0; k0 < IN_F; k0 += 32) {
        __syncthreads();
        #pragma unroll
        for (int q = 0; q < 2; q++) {
            int u   = q * 256 + t;
            int row = u >> 3;
            int kf  = (u & 7) * 4;
            float4 va = *(const float4*)&h[(size_t)(i0 + row) * IN_F + k0 + kf];
            As[kf + 0][row] = va.x; As[kf + 1][row] = va.y;
            As[kf + 2][row] = va.z; As[kf + 3][row] = va.w;
            float4 vb = *(const float4*)&W[(size_t)(n0 + row) * IN_F + k0 + kf];
            Bs[kf + 0][row] = vb.x; Bs[kf + 1][row] = vb.y;
            Bs[kf + 2][row] = vb.z; Bs[kf + 3][row] = vb.w;
        }
        __syncthreads();
        #pragma unroll
        for (int kk = 0; kk < 32; kk++) {
            float a[4], b[4];
            *(float4*)a = *(const float4*)&As[kk][tm * 4];
            *(float4*)b = *(const float4*)&Bs[kk][tn * 4];
            #pragma unroll
            for (int i = 0; i < 4; i++)
                #pragma unroll
                for (int j = 0; j < 4; j++) acc[i][j] = fmaf(a[i], b[j], acc[i][j]);
        }
    }

    #pragma unroll
    for (int ii = 0; ii < 4; ii++) {
        int gr = i0 + tm * 4 + ii;
        int ck = gr >> 5;
        int lr = (gr >> 3) & 3;
        int jj = gr & 7;
        #pragma unroll
        for (int jn = 0; jn < 4; jn++) {
            int gc   = n0 + tn * 4 + jn;
            int c    = ck * 16 + (gc >> 4);
            int lane = (gc & 15) + lr * 16;
            whf[(size_t)c * 512 + lane * 8 + jj] = (uint16_t)f32_to_bf16(acc[ii][jn]);
        }
    }
}

// ---------------------------------------------------------------------------
// K2: adjacency -> phase-interleaved bitmask + softmax denominators l[i].
// mask layout: word (i, jb, ph) bit b  <->  adj[i][jb*256 + b*4 + ph] > 0.
// Block = 1 row, 256 thr, float4 loads (1KB/wave/instr).
// ---------------------------------------------------------------------------
__global__ __launch_bounds__(256) void k2_mask_l(
    const float* __restrict__ adj, const float* __restrict__ s_src,
    const float* __restrict__ s_dst, uint64_t* __restrict__ mask,
    float* __restrict__ l_out)
{
    const int i = blockIdx.x;
    const int t = threadIdx.x, w = t >> 6, ln = t & 63;
    const float si = s_src[i];
    const float4* rowv = (const float4*)(adj + (size_t)i * N_NODES);
    const float4* sdv  = (const float4*)s_dst;
    float acc = 0.f;
    #pragma unroll 2
    for (int it = 0; it < 8; it++) {
        int jb = it * 4 + w;          // 256-j block, 0..31
        int v4 = jb * 64 + ln;
        float4 a  = rowv[v4];
        float4 sd = sdv[v4];
        uint64_t b0 = __ballot(a.x > 0.f);
        uint64_t b1 = __ballot(a.y > 0.f);
        uint64_t b2 = __ballot(a.z > 0.f);
        uint64_t b3 = __ballot(a.w > 0.f);
        if (ln == 0) {
            uint64_t* mw = mask + (size_t)i * 128 + jb * 4;
            mw[0] = b0; mw[1] = b1; mw[2] = b2; mw[3] = b3;
        }
        float x, e;
        x = si + sd.x; e = fmaxf(x, ALPHA * x); if (a.x > 0.f) acc += __expf(e);
        x = si + sd.y; e = fmaxf(x, ALPHA * x); if (a.y > 0.f) acc += __expf(e);
        x = si + sd.z; e = fmaxf(x, ALPHA * x); if (a.z > 0.f) acc += __expf(e);
        x = si + sd.w; e = fmaxf(x, ALPHA * x); if (a.w > 0.f) acc += __expf(e);
    }
    #pragma unroll
    for (int off = 32; off >= 1; off >>= 1) acc += __shfl_xor(acc, off, 64);
    __shared__ float red[4];
    if (ln == 0) red[w] = acc;
    __syncthreads();
    if (t == 0) l_out[i] = (red[0] + red[1]) + (red[2] + red[3]);
}

// ---------------------------------------------------------------------------
// K3: fused attention-write + (attention @ Wh) bf16 MFMA GEMM.
// grid (256 rb, 4 jc), 256 thr. Block: 32 rows x 2048 j, 32 iters of BK=64.
// BARRIER-FREE main loop: whf is 4MB / L2-resident and laid out fragment-
// major, so B-fragments are read straight from global (64x16B coalesced,
// L2 hit) -- no LDS staging, no vmcnt-draining __syncthreads.
// Wave split (mh, kh): mh = row half, kh = j half of the 64-j step. Each
// wave computes ONLY its own 32-j slice of P (exp work not duplicated,
// att store 4-way parallel) and all 16 n-tiles of MFMA. Cross-wave (kh)
// split-K reduced once at the epilogue via LDS.
// ---------------------------------------------------------------------------
__global__ __launch_bounds__(256, 4) void k3_att_gemm(
    const uint64_t* __restrict__ mask, const float* __restrict__ s_src,
    const float* __restrict__ s_dst, const float* __restrict__ l_in,
    const uint16_t* __restrict__ whf, float* __restrict__ att_out,
    float* __restrict__ partial)
{
    const int rb = blockIdx.x, jc = blockIdx.y;
    const int i0 = rb * 32, jbase = jc * 2048;
    const int t = threadIdx.x, w = t >> 6, ln = t & 63;
    const int mh = w & 1, kh = w >> 1;

    const int m   = mh * 16 + (ln & 15);    // row within block, 0..31
    const int kof = (ln >> 4) * 8;          // 0,8,16,24
    const int gi  = i0 + m;

    const float sim = s_src[gi];
    const float il  = 1.0f / l_in[gi];

    f32x4 acc[16];
    #pragma unroll
    for (int b = 0; b < 16; b++) acc[b] = (f32x4){0.f, 0.f, 0.f, 0.f};

    const uint64_t* mrow = mask + (size_t)gi * 128 + (jbase >> 8) * 4;
    uint64_t mwv[4];

    for (int it = 0; it < 32; it++) {
        const int j0 = jbase + it * 64;

        // mask words cover 256 j: reload once per 4 iters (32B/lane, L2 hit)
        if ((it & 3) == 0) {
            const uint64_t* mp = mrow + (it >> 2) * 4;
            mwv[0] = mp[0]; mwv[1] = mp[1]; mwv[2] = mp[2]; mwv[3] = mp[3];
        }

        // this wave's 8 s_dst values (L1-resident, 32KB array)
        const float* sp = s_dst + j0 + kh * 32 + kof;
        float4 sd0 = *(const float4*)sp;
        float4 sd1 = *(const float4*)(sp + 4);
        float sdv[8] = {sd0.x, sd0.y, sd0.z, sd0.w, sd1.x, sd1.y, sd1.z, sd1.w};

        const int bbase = ((it & 3) << 4) + (kh << 3) + (kof >> 2);
        float p[8];
        #pragma unroll
        for (int jj = 0; jj < 8; jj++) {
            float x  = sim + sdv[jj];
            float e  = fmaxf(x, ALPHA * x);
            float pe = __expf(e) * il;
            int bidx = bbase + (jj >> 2);
            p[jj] = ((mwv[jj & 3] >> bidx) & 1ull) ? pe : 0.f;
        }

        // att store: each wave owns its disjoint 32-j slice (nontemporal)
        float* go = att_out + (size_t)gi * N_NODES + j0 + kh * 32 + kof;
        __builtin_nontemporal_store(*(f32x4*)&p[0], (f32x4*)go);
        __builtin_nontemporal_store(*(f32x4*)&p[4], (f32x4*)(go + 4));

        // pack A-fragment to bf16
        union { bf16x8 v; uint32_t u[4]; } pk;
        #pragma unroll
        for (int q = 0; q < 4; q++)
            pk.u[q] = f32_to_bf16(p[2 * q]) | (f32_to_bf16(p[2 * q + 1]) << 16);
        bf16x8 af = pk.v;

        // B-fragments straight from global: 64 lanes x 16B contiguous, L2 hit
        const uint16_t* src = whf + (((size_t)(j0 >> 5) + kh) << 13) + ln * 8;
        #pragma unroll
        for (int nl = 0; nl < 16; nl++) {
            bf16x8 bfr = *(const bf16x8*)(src + nl * 512);
            acc[nl] = __builtin_amdgcn_mfma_f32_16x16x32_bf16(af, bfr, acc[nl], 0, 0, 0);
        }
    }

    // epilogue: reduce kh=1 into kh=0 via LDS, then store partial[jc].
    // C/D frag: col = lane&15, row = (lane>>4)*4 + reg.
    __shared__ float red[2][16][257];
    const int lr = (ln >> 4) * 4;
    if (kh == 1) {
        #pragma unroll
        for (int nl = 0; nl < 16; nl++)
            #pragma unroll
            for (int r = 0; r < 4; r++)
                red[mh][lr + r][nl * 16 + (ln & 15)] = acc[nl][r];
    }
    __syncthreads();
    if (kh == 0) {
        float* pbase = partial + (size_t)jc * ((size_t)N_NODES * OUT_F);
        const int gr0 = i0 + mh * 16 + lr;
        #pragma unroll
        for (int nl = 0; nl < 16; nl++) {
            int gc = nl * 16 + (ln & 15);
            #pragma unroll
            for (int r = 0; r < 4; r++)
                pbase[(size_t)(gr0 + r) * OUT_F + gc] = acc[nl][r] + red[mh][lr + r][gc];
        }
    }
}

// ---------------------------------------------------------------------------
// K4: h_prime = sum of 4 split-K partials
// ---------------------------------------------------------------------------
__global__ __launch_bounds__(256) void k4_reduce(
    const float* __restrict__ partial, float* __restrict__ hp)
{
    const size_t S = (size_t)N_NODES * OUT_F;
    int idx = (blockIdx.x * 256 + threadIdx.x) * 4;
    float4 a = *(const float4*)(partial + idx);
    float4 b = *(const float4*)(partial + S + idx);
    float4 c = *(const float4*)(partial + 2 * S + idx);
    float4 d = *(const float4*)(partial + 3 * S + idx);
    float4 o;
    o.x = (a.x + b.x) + (c.x + d.x);
    o.y = (a.y + b.y) + (c.y + d.y);
    o.z = (a.z + b.z) + (c.z + d.z);
    o.w = (a.w + b.w) + (c.w + d.w);
    *(float4*)(hp + idx) = o;
}

extern "C" void kernel_launch(void* const* d_in, const int* in_sizes, int n_in,
                              void* d_out, int out_size, void* d_ws, size_t ws_size,
                              hipStream_t stream) {
    (void)in_sizes; (void)n_in; (void)out_size; (void)ws_size;
    const float* h     = (const float*)d_in[0];
    const float* adj   = (const float*)d_in[1];
    const float* W     = (const float*)d_in[2];
    const float* a_vec = (const float*)d_in[3];

    char* ws = (char*)d_ws;
    uint16_t* whf  = (uint16_t*)(ws);                          // 4 MB
    uint64_t* mask = (uint64_t*)(ws + ((size_t)4 << 20));      // 8 MB
    float* partial = (float*)(ws + ((size_t)12 << 20));        // 32 MB
    float* w12     = (float*)(ws + ((size_t)44 << 20));        // 4 KB
    float* s_src   = (float*)(ws + ((size_t)44 << 20) + 16384);
    float* s_dst   = (float*)(ws + ((size_t)44 << 20) + 16384 + 32768);
    float* l_buf   = (float*)(ws + ((size_t)44 << 20) + 16384 + 65536);

    float* hp  = (float*)d_out;
    float* att = hp + (size_t)N_NODES * OUT_F;

    hipMemsetAsync(w12, 0, 4096, stream);
    k0_wvec<<<32, 256, 0, stream>>>(W, a_vec, w12);
    ks_svec<<<2048, 256, 0, stream>>>(h, w12, s_src, s_dst);
    k1_wh_pack<<<dim3(4, 128), 256, 0, stream>>>(h, W, whf);
    k2_mask_l<<<8192, 256, 0, stream>>>(adj, s_src, s_dst, mask, l_buf);
    k3_att_gemm<<<dim3(256, 4), 256, 0, stream>>>(mask, s_src, s_dst, l_buf, whf, att, partial);
    k4_reduce<<<2048, 256, 0, stream>>>(partial, hp);
}

// Round 2
// 682.473 us; speedup vs baseline: 1.0658x; 1.0658x over previous
//
#include <hip/hip_runtime.h>
#include <stdint.h>

#define N_NODES 8192
#define IN_F    512
#define OUT_F   256
#define ALPHA   0.2f

typedef __attribute__((ext_vector_type(8))) short bf16x8;
typedef __attribute__((ext_vector_type(4))) float f32x4;

__device__ __forceinline__ uint32_t f32_to_bf16(float f) {
    union { float f; uint32_t u; } v; v.f = f;
    uint32_t u = v.u;
    return (u + 0x7fffu + ((u >> 16) & 1u)) >> 16;   // RNE
}

// async global->LDS, 16B per lane; LDS dest = uniform base + lane*16
__device__ __forceinline__ void async_copy16(const void* g, void* l) {
    __builtin_amdgcn_global_load_lds(
        (const __attribute__((address_space(1))) uint32_t*)g,
        (__attribute__((address_space(3))) uint32_t*)l, 16, 0, 0);
}

// ---------------------------------------------------------------------------
// K0: w1 = W^T a1, w2 = W^T a2  (w12[0:512]=w1, w12[512:1024]=w2)
// ---------------------------------------------------------------------------
__global__ __launch_bounds__(256) void k0_wvec(
    const float* __restrict__ W, const float* __restrict__ a_vec,
    float* __restrict__ w12)
{
    const int t  = threadIdx.x;
    const int nb = blockIdx.x * 8;
    float a1lo = 0.f, a1hi = 0.f, a2lo = 0.f, a2hi = 0.f;
    #pragma unroll
    for (int q = 0; q < 8; q++) {
        int n = nb + q;
        float lo = W[(size_t)n * IN_F + t];
        float hi = W[(size_t)n * IN_F + t + 256];
        float a1 = a_vec[n], a2 = a_vec[OUT_F + n];
        a1lo = fmaf(lo, a1, a1lo); a1hi = fmaf(hi, a1, a1hi);
        a2lo = fmaf(lo, a2, a2lo); a2hi = fmaf(hi, a2, a2hi);
    }
    atomicAdd(&w12[t], a1lo);       atomicAdd(&w12[t + 256], a1hi);
    atomicAdd(&w12[512 + t], a2lo); atomicAdd(&w12[512 + t + 256], a2hi);
}

// ---------------------------------------------------------------------------
// Ks: s_src[i] = h[i] . w1 ; s_dst[i] = h[i] . w2   (1 wave per row)
// ---------------------------------------------------------------------------
__global__ __launch_bounds__(256) void ks_svec(
    const float* __restrict__ h, const float* __restrict__ w12,
    float* __restrict__ s_src, float* __restrict__ s_dst)
{
    __shared__ float sw[1024];
    const int t = threadIdx.x;
    #pragma unroll
    for (int q = 0; q < 4; q++) sw[q * 256 + t] = w12[q * 256 + t];
    __syncthreads();
    const int w = t >> 6, ln = t & 63;
    const int i = blockIdx.x * 4 + w;
    const float* hr = h + (size_t)i * IN_F + ln * 8;
    float4 h0 = *(const float4*)hr;
    float4 h1 = *(const float4*)(hr + 4);
    const float* w1 = sw + ln * 8;
    const float* w2 = sw + 512 + ln * 8;
    float v1 = h0.x*w1[0] + h0.y*w1[1] + h0.z*w1[2] + h0.w*w1[3]
             + h1.x*w1[4] + h1.y*w1[5] + h1.z*w1[6] + h1.w*w1[7];
    float v2 = h0.x*w2[0] + h0.y*w2[1] + h0.z*w2[2] + h0.w*w2[3]
             + h1.x*w2[4] + h1.y*w2[5] + h1.z*w2[6] + h1.w*w2[7];
    #pragma unroll
    for (int off = 32; off >= 1; off >>= 1) {
        v1 += __shfl_xor(v1, off, 64);
        v2 += __shfl_xor(v2, off, 64);
    }
    if (ln == 0) { s_src[i] = v1; s_dst[i] = v2; }
}

// ---------------------------------------------------------------------------
// K1: Wh = h @ W^T (fp32) -> whf bf16 in MFMA-B-fragment-major layout.
// chunk c = (j>>5)*16 + (n>>4); within: lane = (n&15) + ((j>>3)&3)*16,
// element = lane*8 + (j&7).   grid (4 colblk, 128 rowblk), 256 thr, 4x4/thr.
// LDS stride 68 (=17*16B): keeps &As[kk][tm*4] 16B-aligned -> ds_read_b128.
// ---------------------------------------------------------------------------
__global__ __launch_bounds__(256) void k1_wh_pack(
    const float* __restrict__ h, const float* __restrict__ W,
    uint16_t* __restrict__ whf)
{
    const int n0 = blockIdx.x * 64, i0 = blockIdx.y * 64;
    const int t  = threadIdx.x;
    const int tn = t & 15, tm = t >> 4;

    __shared__ float As[32][68];
    __shared__ float Bs[32][68];

    float acc[4][4];
    #pragma unroll
    for (int i = 0; i < 4; i++)
        #pragma unroll
        for (int j = 0; j < 4; j++) acc[i][j] = 0.f;

    for (int k0 = 0; k0 < IN_F; k0 += 32) {
        __syncthreads();
        #pragma unroll
        for (int q = 0; q < 2; q++) {
            int u   = q * 256 + t;
            int row = u >> 3;
            int kf  = (u & 7) * 4;
            float4 va = *(const float4*)&h[(size_t)(i0 + row) * IN_F + k0 + kf];
            As[kf + 0][row] = va.x; As[kf + 1][row] = va.y;
            As[kf + 2][row] = va.z; As[kf + 3][row] = va.w;
            float4 vb = *(const float4*)&W[(size_t)(n0 + row) * IN_F + k0 + kf];
            Bs[kf + 0][row] = vb.x; Bs[kf + 1][row] = vb.y;
            Bs[kf + 2][row] = vb.z; Bs[kf + 3][row] = vb.w;
        }
        __syncthreads();
        #pragma unroll
        for (int kk = 0; kk < 32; kk++) {
            float a[4], b[4];
            *(float4*)a = *(const float4*)&As[kk][tm * 4];
            *(float4*)b = *(const float4*)&Bs[kk][tn * 4];
            #pragma unroll
            for (int i = 0; i < 4; i++)
                #pragma unroll
                for (int j = 0; j < 4; j++) acc[i][j] = fmaf(a[i], b[j], acc[i][j]);
        }
    }

    #pragma unroll
    for (int ii = 0; ii < 4; ii++) {
        int gr = i0 + tm * 4 + ii;
        int ck = gr >> 5;
        int lr = (gr >> 3) & 3;
        int jj = gr & 7;
        #pragma unroll
        for (int jn = 0; jn < 4; jn++) {
            int gc   = n0 + tn * 4 + jn;
            int c    = ck * 16 + (gc >> 4);
            int lane = (gc & 15) + lr * 16;
            whf[(size_t)c * 512 + lane * 8 + jj] = (uint16_t)f32_to_bf16(acc[ii][jn]);
        }
    }
}

// ---------------------------------------------------------------------------
// K2: adjacency -> phase-interleaved bitmask + softmax denominators l[i].
// mask layout: word (i, jb, ph) bit b  <->  adj[i][jb*256 + b*4 + ph] > 0.
// Block = 1 row, 256 thr, float4 loads, FULL unroll (8 loads in flight).
// ---------------------------------------------------------------------------
__global__ __launch_bounds__(256) void k2_mask_l(
    const float* __restrict__ adj, const float* __restrict__ s_src,
    const float* __restrict__ s_dst, uint64_t* __restrict__ mask,
    float* __restrict__ l_out)
{
    const int i = blockIdx.x;
    const int t = threadIdx.x, w = t >> 6, ln = t & 63;
    const float si = s_src[i];
    const float4* rowv = (const float4*)(adj + (size_t)i * N_NODES);
    const float4* sdv  = (const float4*)s_dst;
    float acc = 0.f;
    #pragma unroll
    for (int it = 0; it < 8; it++) {
        int jb = it * 4 + w;          // 256-j block, 0..31
        int v4 = jb * 64 + ln;
        float4 a  = rowv[v4];
        float4 sd = sdv[v4];
        uint64_t b0 = __ballot(a.x > 0.f);
        uint64_t b1 = __ballot(a.y > 0.f);
        uint64_t b2 = __ballot(a.z > 0.f);
        uint64_t b3 = __ballot(a.w > 0.f);
        if (ln == 0) {
            uint64_t* mw = mask + (size_t)i * 128 + jb * 4;
            mw[0] = b0; mw[1] = b1; mw[2] = b2; mw[3] = b3;
        }
        float x, e;
        x = si + sd.x; e = fmaxf(x, ALPHA * x); if (a.x > 0.f) acc += __expf(e);
        x = si + sd.y; e = fmaxf(x, ALPHA * x); if (a.y > 0.f) acc += __expf(e);
        x = si + sd.z; e = fmaxf(x, ALPHA * x); if (a.z > 0.f) acc += __expf(e);
        x = si + sd.w; e = fmaxf(x, ALPHA * x); if (a.w > 0.f) acc += __expf(e);
    }
    #pragma unroll
    for (int off = 32; off >= 1; off >>= 1) acc += __shfl_xor(acc, off, 64);
    __shared__ float red[4];
    if (ln == 0) red[w] = acc;
    __syncthreads();
    if (t == 0) l_out[i] = (red[0] + red[1]) + (red[2] + red[3]);
}

// ---------------------------------------------------------------------------
// K3: fused attention-write + (attention @ Wh) bf16 MFMA GEMM.
// grid (256 rb, 4 jc), 256 thr. Block: 32 rows x 2048 j, 32 iters of BK=64.
// 2-phase pipeline (T3 recipe): double-buffered LDS staging via
// global_load_lds; tile t+1 staged at TOP of iter t, consumed next iter, so
// the single vmcnt(0)+s_barrier at the bottom waits on a DMA that has had
// the whole compute phase to land. One barrier/iter (vs 2 in round 0).
// Wave split (mh, kh): mh = row half, kh = j half. Each wave computes only
// its own 32-j slice of P (no duplicate exp; att store 4-way parallel) and
// all 16 n-tiles of MFMA; kh halves split-K reduced at the epilogue via LDS
// aliased into whf_lds (so LDS = 64 KB -> 2 blocks/CU).
// ---------------------------------------------------------------------------
__global__ __launch_bounds__(256, 2) void k3_att_gemm(
    const uint64_t* __restrict__ mask, const float* __restrict__ s_src,
    const float* __restrict__ s_dst, const float* __restrict__ l_in,
    const uint16_t* __restrict__ whf, float* __restrict__ att_out,
    float* __restrict__ partial)
{
    const int rb = blockIdx.x, jc = blockIdx.y;
    const int i0 = rb * 32, jbase = jc * 2048;
    const int t = threadIdx.x, w = t >> 6, ln = t & 63;
    const int mh = w & 1, kh = w >> 1;

    __shared__ uint16_t whf_lds[2][16384];   // 2 x 32 KB; aliased by epilogue

    const int m   = mh * 16 + (ln & 15);    // row within block, 0..31
    const int kof = (ln >> 4) * 8;          // 0,8,16,24
    const int gi  = i0 + m;

    const float sim = s_src[gi];
    const float il  = 1.0f / l_in[gi];

    f32x4 acc[16];
    #pragma unroll
    for (int b = 0; b < 16; b++) acc[b] = (f32x4){0.f, 0.f, 0.f, 0.f};

    const uint64_t* mrow = mask + (size_t)gi * 128 + (jbase >> 8) * 4;
    uint64_t mwv[4];

    // prologue: stage tile 0 into buf 0
    {
        const uint16_t* src = whf + ((size_t)(jbase >> 5)) * 8192;
        #pragma unroll
        for (int q = 0; q < 8; q++) {
            int c = w * 8 + q;
            async_copy16(src + (size_t)c * 512 + ln * 8, &whf_lds[0][c * 512]);
        }
        asm volatile("s_waitcnt vmcnt(0)" ::: "memory");
        __builtin_amdgcn_s_barrier();
    }

    for (int it = 0; it < 32; it++) {
        const int j0  = jbase + it * 64;
        const int cur = it & 1;

        // stage NEXT tile first (latency hides under this iter's compute)
        if (it < 31) {
            const uint16_t* src = whf + ((size_t)((j0 + 64) >> 5)) * 8192;
            #pragma unroll
            for (int q = 0; q < 8; q++) {
                int c = w * 8 + q;
                async_copy16(src + (size_t)c * 512 + ln * 8,
                             &whf_lds[cur ^ 1][c * 512]);
            }
        }

        // mask words cover 256 j: reload once per 4 iters (L2 hit)
        if ((it & 3) == 0) {
            const uint64_t* mp = mrow + (it >> 2) * 4;
            mwv[0] = mp[0]; mwv[1] = mp[1]; mwv[2] = mp[2]; mwv[3] = mp[3];
        }

        // this wave's 8 s_dst values (L1-resident, 32 KB array)
        const float* sp = s_dst + j0 + kh * 32 + kof;
        float4 sd0 = *(const float4*)sp;
        float4 sd1 = *(const float4*)(sp + 4);
        float sdv[8] = {sd0.x, sd0.y, sd0.z, sd0.w, sd1.x, sd1.y, sd1.z, sd1.w};

        const int bbase = ((it & 3) << 4) + (kh << 3) + (kof >> 2);
        float p[8];
        #pragma unroll
        for (int jj = 0; jj < 8; jj++) {
            float x  = sim + sdv[jj];
            float e  = fmaxf(x, ALPHA * x);
            float pe = __expf(e) * il;
            int bidx = bbase + (jj >> 2);
            p[jj] = ((mwv[jj & 3] >> bidx) & 1ull) ? pe : 0.f;
        }

        // att store: each wave owns its disjoint 32-j slice (nontemporal)
        float* go = att_out + (size_t)gi * N_NODES + j0 + kh * 32 + kof;
        __builtin_nontemporal_store(*(f32x4*)&p[0], (f32x4*)go);
        __builtin_nontemporal_store(*(f32x4*)&p[4], (f32x4*)(go + 4));

        // pack A-fragment to bf16
        union { bf16x8 v; uint32_t u[4]; } pk;
        #pragma unroll
        for (int q = 0; q < 4; q++)
            pk.u[q] = f32_to_bf16(p[2 * q]) | (f32_to_bf16(p[2 * q + 1]) << 16);
        bf16x8 af = pk.v;

        // B-fragments from LDS (this wave's kh half: 16 KB, conflict-free)
        const uint16_t* bl = &whf_lds[cur][kh * 8192 + ln * 8];
        #pragma unroll
        for (int nl = 0; nl < 16; nl++) {
            bf16x8 bfr = *(const bf16x8*)(bl + nl * 512);
            acc[nl] = __builtin_amdgcn_mfma_f32_16x16x32_bf16(af, bfr, acc[nl], 0, 0, 0);
        }

        // my DMA (and stores) drained, then rendezvous: next buf is ready
        asm volatile("s_waitcnt vmcnt(0)" ::: "memory");
        __builtin_amdgcn_s_barrier();
    }

    // epilogue: reduce kh=1 into kh=0 via LDS (aliased over whf_lds).
    // C/D frag: col = lane&15, row = (lane>>4)*4 + reg.
    __syncthreads();   // all MFMA ds_reads done before overwriting whf_lds
    float (*red)[16][257] = (float (*)[16][257])whf_lds;   // 2*16*257*4 B
    const int lr = (ln >> 4) * 4;
    if (kh == 1) {
        #pragma unroll
        for (int nl = 0; nl < 16; nl++)
            #pragma unroll
            for (int r = 0; r < 4; r++)
                red[mh][lr + r][nl * 16 + (ln & 15)] = acc[nl][r];
    }
    __syncthreads();
    if (kh == 0) {
        float* pbase = partial + (size_t)jc * ((size_t)N_NODES * OUT_F);
        const int gr0 = i0 + mh * 16 + lr;
        #pragma unroll
        for (int nl = 0; nl < 16; nl++) {
            int gc = nl * 16 + (ln & 15);
            #pragma unroll
            for (int r = 0; r < 4; r++)
                pbase[(size_t)(gr0 + r) * OUT_F + gc] = acc[nl][r] + red[mh][lr + r][gc];
        }
    }
}

// ---------------------------------------------------------------------------
// K4: h_prime = sum of 4 split-K partials
// ---------------------------------------------------------------------------
__global__ __launch_bounds__(256) void k4_reduce(
    const float* __restrict__ partial, float* __restrict__ hp)
{
    const size_t S = (size_t)N_NODES * OUT_F;
    int idx = (blockIdx.x * 256 + threadIdx.x) * 4;
    float4 a = *(const float4*)(partial + idx);
    float4 b = *(const float4*)(partial + S + idx);
    float4 c = *(const float4*)(partial + 2 * S + idx);
    float4 d = *(const float4*)(partial + 3 * S + idx);
    float4 o;
    o.x = (a.x + b.x) + (c.x + d.x);
    o.y = (a.y + b.y) + (c.y + d.y);
    o.z = (a.z + b.z) + (c.z + d.z);
    o.w = (a.w + b.w) + (c.w + d.w);
    *(float4*)(hp + idx) = o;
}

extern "C" void kernel_launch(void* const* d_in, const int* in_sizes, int n_in,
                              void* d_out, int out_size, void* d_ws, size_t ws_size,
                              hipStream_t stream) {
    (void)in_sizes; (void)n_in; (void)out_size; (void)ws_size;
    const float* h     = (const float*)d_in[0];
    const float* adj   = (const float*)d_in[1];
    const float* W     = (const float*)d_in[2];
    const float* a_vec = (const float*)d_in[3];

    char* ws = (char*)d_ws;
    uint16_t* whf  = (uint16_t*)(ws);                          // 4 MB
    uint64_t* mask = (uint64_t*)(ws + ((size_t)4 << 20));      // 8 MB
    float* partial = (float*)(ws + ((size_t)12 << 20));        // 32 MB
    float* w12     = (float*)(ws + ((size_t)44 << 20));        // 4 KB
    float* s_src   = (float*)(ws + ((size_t)44 << 20) + 16384);
    float* s_dst   = (float*)(ws + ((size_t)44 << 20) + 16384 + 32768);
    float* l_buf   = (float*)(ws + ((size_t)44 << 20) + 16384 + 65536);

    float* hp  = (float*)d_out;
    float* att = hp + (size_t)N_NODES * OUT_F;

    hipMemsetAsync(w12, 0, 4096, stream);
    k0_wvec<<<32, 256, 0, stream>>>(W, a_vec, w12);
    ks_svec<<<2048, 256, 0, stream>>>(h, w12, s_src, s_dst);
    k1_wh_pack<<<dim3(4, 128), 256, 0, stream>>>(h, W, whf);
    k2_mask_l<<<8192, 256, 0, stream>>>(adj, s_src, s_dst, mask, l_buf);
    k3_att_gemm<<<dim3(256, 4), 256, 0, stream>>>(mask, s_src, s_dst, l_buf, whf, att, partial);
    k4_reduce<<<2048, 256, 0, stream>>>(partial, hp);
}